// Round 3
// baseline (7108.203 us; speedup 1.0000x reference)
//
#include <hip/hip_runtime.h>

#define T_STEPS 8192
#define BATCH   128
#define HID     128
#define NTHR    256               // 4 waves, 1/SIMD

typedef float v2f __attribute__((ext_vector_type(2)));

// tanh(z) = 1 - 2/(1+e^{2z}) -- 5 instrs, NaN-free at both infinities.
__device__ __forceinline__ float fast_tanh(float z) {
    float e = __expf(2.0f * z);
    float r = __builtin_amdgcn_rcpf(1.0f + e);
    return fmaf(-2.0f, r, 1.0f);
}

// sum the 2 lanes of a pair (xor1 within quad); both lanes get the result.
__device__ __forceinline__ float pair_sum(float x) {
    int t1 = __builtin_amdgcn_update_dpp(0, __builtin_bit_cast(int, x),
                                         0xB1 /*quad_perm [1,0,3,2]*/,
                                         0xf, 0xf, false);
    return x + __builtin_bit_cast(float, t1);
}

// wave sum of PAIR-UNIFORM values -> total lands in lane 63 (5 DPP adds).
__device__ __forceinline__ float wave_sum_pairuniform_l63(float x) {
#define DPP_ADD(ctrl) do {                                                        \
        int t_ = __builtin_amdgcn_update_dpp(0, __builtin_bit_cast(int, x),       \
                                             (ctrl), 0xf, 0xf, false);            \
        x += __builtin_bit_cast(float, t_); } while (0)
    DPP_ADD(0x112);  // row_shr:2
    DPP_ADD(0x114);  // row_shr:4
    DPP_ADD(0x118);  // row_shr:8   -> row sums at row tails
    DPP_ADD(0x142);  // row_bcast:15
    DPP_ADD(0x143);  // row_bcast:31 -> lane 63 holds wave total
#undef DPP_ADD
    return x;
}

__device__ __forceinline__ float bcast_lane(float v, int l) {
    int r = __builtin_amdgcn_readlane(__builtin_bit_cast(int, v), l);
    return __builtin_bit_cast(float, r);
}

#define FORALL32(M) M(0) M(1) M(2) M(3) M(4) M(5) M(6) M(7) \
                    M(8) M(9) M(10) M(11) M(12) M(13) M(14) M(15) \
                    M(16) M(17) M(18) M(19) M(20) M(21) M(22) M(23) \
                    M(24) M(25) M(26) M(27) M(28) M(29) M(30) M(31)

// one 16-B read of an h1 chunk + two packed FMAs into the running v2f accs
#define FMAP(H4, qi, WA, WB, AA, AB) {                                            \
        float4 q_ = (H4)[qi];                                                     \
        v2f lo_ = {q_.x, q_.y}, hi_ = {q_.z, q_.w};                               \
        AA += (WA) * lo_; AB += (WB) * hi_; }

// full 64-float (own s-chunk) dot against the pinned W2 fragment -> AP (v2f)
#define L2DOT(H4, AP) do {                                                        \
        v2f a0_={0.f,0.f}, a1_={0.f,0.f}, a2_={0.f,0.f}, a3_={0.f,0.f};           \
        FMAP(H4, 0, wp0 , wp1 , a0_, a1_) FMAP(H4, 1, wp2 , wp3 , a2_, a3_)       \
        FMAP(H4, 2, wp4 , wp5 , a0_, a1_) FMAP(H4, 3, wp6 , wp7 , a2_, a3_)       \
        FMAP(H4, 4, wp8 , wp9 , a0_, a1_) FMAP(H4, 5, wp10, wp11, a2_, a3_)       \
        FMAP(H4, 6, wp12, wp13, a0_, a1_) FMAP(H4, 7, wp14, wp15, a2_, a3_)       \
        FMAP(H4, 8, wp16, wp17, a0_, a1_) FMAP(H4, 9, wp18, wp19, a2_, a3_)       \
        FMAP(H4,10, wp20, wp21, a0_, a1_) FMAP(H4,11, wp22, wp23, a2_, a3_)       \
        FMAP(H4,12, wp24, wp25, a0_, a1_) FMAP(H4,13, wp26, wp27, a2_, a3_)       \
        FMAP(H4,14, wp28, wp29, a0_, a1_) FMAP(H4,15, wp30, wp31, a2_, a3_)       \
        AP = (a0_ + a1_) + (a2_ + a3_); } while (0)

// R17b (compile fix: batch-element locals renamed be0/be1 -- `b1` collided
// with the bias-pointer parameter). Interleave TWO independent batch elements
// per block (64 blocks x 2). The per-step serial chain (~85% stall at R16:
// LDS round trips, DPP reduce, barrier, trans-op latency) is unchanged per
// element, but element 1's instructions issue inside element 0's stalls, and
// the s_barrier + lgkmcnt(0) drain is amortized over both dy exchanges.
// Weights (64 pinned VGPRs) are shared; per-element marginal state ~15 VGPRs.
// Arithmetic per element is bit-identical to R16.
__global__ __launch_bounds__(NTHR, 2) void odenet_scan(
    const float* __restrict__ x,
    const float* __restrict__ W1, const float* __restrict__ b1,
    const float* __restrict__ W2, const float* __restrict__ b2,
    const float* __restrict__ W3, const float* __restrict__ b3,
    float* __restrict__ out) {

    const int be0  = blockIdx.x * 2;    // batch elements be0, be1
    const int be1  = be0 + 1;
    const int tid  = threadIdx.x;
    const int w    = tid >> 6;          // wave 0..3
    const int lane = tid & 63;
    const int j    = (w << 5) | (lane >> 1);   // owned output unit
    const int s    = lane & 1;                 // k-chunk [64s, 64s+64)

    // wave-private h1 per element: 2 chunks x 68 floats (64 + 4 pad)
    __shared__ __align__(16) float h1buf[2][4][136];   // [elem][wave][...]
    __shared__ __align__(16) float dyx[2][2][4];       // [parity][elem][wave]

    // ---- W2 fragment: rows [64s, 64s+64) of column j, packed as 32 v2f ----
    const float* col = W2 + j;          // column j, row stride HID
    const int kb = s << 6;
#define DECLW(i) v2f wp##i = {col[(kb + 2*(i) + 0) * HID],                        \
                              col[(kb + 2*(i) + 1) * HID]};
    FORALL32(DECLW)
#undef DECLW
#define PINW(i) asm volatile("" : "+v"(wp##i));
    FORALL32(PINW)
#undef PINW

    // layer-1 weights for the two h1 units this lane computes (k=lane, lane+64)
    float w1xa = W1[lane],      w1ya = W1[HID + lane],      b1a = b1[lane];
    float w1xb = W1[lane + 64], w1yb = W1[HID + lane + 64], b1b = b1[lane + 64];
    float b2j = b2[j], w3j = W3[j], b3v = b3[0];
    asm volatile("" : "+v"(w1xa), "+v"(w1ya), "+v"(b1a),
                      "+v"(w1xb), "+v"(w1yb), "+v"(b1b),
                      "+v"(b2j), "+v"(w3j), "+v"(b3v));

    float y0 = 0.0f, y1 = 0.0f;
    float ybuf0 = 0.0f, ybuf1 = 0.0f;   // all waves capture (symmetric arrival)
    if (w == 0 && lane == 0) { out[be0] = 0.0f; out[be1] = 0.0f; }   // y_0 = 0

    // ---- x double-buffer per element ----
    float xbuf0 = x[lane * BATCH + be0];
    float xbuf1 = x[lane * BATCH + be1];
    int   nb    = 64;                                  // next block base
    float xnext0 = x[min(nb + lane, T_STEPS - 1) * BATCH + be0];
    float xnext1 = x[min(nb + lane, T_STEPS - 1) * BATCH + be1];
    float xv0 = bcast_lane(xbuf0, 0);
    float xv1 = bcast_lane(xbuf1, 0);
    float ax0 = fmaf(xv0, w1xa, b1a);   // x-side of layer 1 for t=0
    float bx0 = fmaf(xv0, w1xb, b1b);
    float ax1 = fmaf(xv1, w1xa, b1a);
    float bx1 = fmaf(xv1, w1xb, b1b);

    const float4* h40 = (const float4*)&h1buf[0][w][s * 68];
    const float4* h41 = (const float4*)&h1buf[1][w][s * 68];

    for (int t = 0; t < T_STEPS - 1; ++t) {
        const int tm = t & 63;
        const int p  = t & 1;

        // ---- layer 1, both elements (critical path from y: fma+tanh+write) --
        float ha0 = fast_tanh(fmaf(y0, w1ya, ax0));
        float hb0 = fast_tanh(fmaf(y0, w1yb, bx0));
        h1buf[0][w][lane]      = ha0;
        h1buf[0][w][68 + lane] = hb0;
        float ha1 = fast_tanh(fmaf(y1, w1ya, ax1));
        float hb1 = fast_tanh(fmaf(y1, w1yb, bx1));
        h1buf[1][w][lane]      = ha1;
        h1buf[1][w][68 + lane] = hb1;

        // ---- layer 2 + reduce, element 0 ----
        v2f ap0;
        L2DOT(h40, ap0);
        float z20  = pair_sum(ap0.x + ap0.y);        // full dot for unit j
        float h20  = fast_tanh(z20 + b2j);
        float dyw0 = wave_sum_pairuniform_l63(w3j * h20);
        if (lane == 63) dyx[p][0][w] = dyw0;

        // ---- layer 2 + reduce, element 1 (issues inside e0's stalls) ----
        v2f ap1;
        L2DOT(h41, ap1);
        float z21  = pair_sum(ap1.x + ap1.y);
        float h21  = fast_tanh(z21 + b2j);
        float dyw1 = wave_sum_pairuniform_l63(w3j * h21);
        if (lane == 63) dyx[p][1][w] = dyw1;

        // ---- next step's x-side prep (y-independent; fills barrier wait) ----
        const int tmn = (t + 1) & 63;
        if (tmn == 0) {                              // rotate x blocks
            xbuf0 = xnext0;
            xbuf1 = xnext1;
            nb += 64;
            const int xi = min(nb + lane, T_STEPS - 1) * BATCH;
            xnext0 = x[xi + be0];
            xnext1 = x[xi + be1];
        }
        float xvn0 = bcast_lane(xbuf0, tmn);
        float xvn1 = bcast_lane(xbuf1, tmn);
        float axn0 = fmaf(xvn0, w1xa, b1a);
        float bxn0 = fmaf(xvn0, w1xb, b1b);
        float axn1 = fmaf(xvn1, w1xa, b1a);
        float bxn1 = fmaf(xvn1, w1xb, b1b);

        // ---- ONE lgkm-only barrier covers both elements' exchanges ----
        asm volatile("s_waitcnt lgkmcnt(0)\n\ts_barrier" ::: "memory");

        float4 d0 = *(const float4*)&dyx[p][0][0];   // one broadcast b128 each
        float4 d1 = *(const float4*)&dyx[p][1][0];
        y0 += ((d0.x + d0.y) + (d0.z + d0.w)) + b3v; // DT = 1.0
        y1 += ((d1.x + d1.y) + (d1.z + d1.w)) + b3v;

        ybuf0 = (lane == tm) ? y0 : ybuf0;           // all waves (symmetric)
        ybuf1 = (lane == tm) ? y1 : ybuf1;
        if (tm == 63) {
            if (w == 0)      out[(t - 62 + lane) * BATCH + be0] = ybuf0;
            else if (w == 1) out[(t - 62 + lane) * BATCH + be1] = ybuf1;
        }

        ax0 = axn0; bx0 = bxn0;
        ax1 = axn1; bx1 = bxn1;
    }
    // tail: t=8128..8190 captured y_8129..y_8191 in lanes 0..62
    if (lane < 63) {
        if (w == 0)      out[(T_STEPS - 63 + lane) * BATCH + be0] = ybuf0;
        else if (w == 1) out[(T_STEPS - 63 + lane) * BATCH + be1] = ybuf1;
    }
}

extern "C" void kernel_launch(void* const* d_in, const int* in_sizes, int n_in,
                              void* d_out, int out_size, void* d_ws, size_t ws_size,
                              hipStream_t stream) {
    const float* x  = (const float*)d_in[0];
    const float* W1 = (const float*)d_in[1];
    const float* b1 = (const float*)d_in[2];
    const float* W2 = (const float*)d_in[3];
    const float* b2 = (const float*)d_in[4];
    const float* W3 = (const float*)d_in[5];
    const float* b3 = (const float*)d_in[6];

    odenet_scan<<<dim3(BATCH / 2), dim3(NTHR), 0, stream>>>(
        x, W1, b1, W2, b2, W3, b3, (float*)d_out);
}

// Round 4
// 3556.548 us; speedup vs baseline: 1.9986x; 1.9986x over previous
//
#include <hip/hip_runtime.h>

#define T_STEPS 8192
#define BATCH   128
#define HID     128
#define NTHR    256               // 4 waves, 1/SIMD

typedef float v2f __attribute__((ext_vector_type(2)));

// tanh(z) = 1 - 2/(1+e^{2z}) -- 5 instrs, NaN-free at both infinities.
__device__ __forceinline__ float fast_tanh(float z) {
    float e = __expf(2.0f * z);
    float r = __builtin_amdgcn_rcpf(1.0f + e);
    return fmaf(-2.0f, r, 1.0f);
}

// butterfly sum across a quad (lanes 4q..4q+3): xor1 then xor2 quad_perm.
// all 4 lanes end with the full quad sum.
__device__ __forceinline__ float quad_sum(float x) {
    int t1 = __builtin_amdgcn_update_dpp(0, __builtin_bit_cast(int, x),
                                         0xB1 /*quad_perm [1,0,3,2]*/,
                                         0xf, 0xf, false);
    x += __builtin_bit_cast(float, t1);
    int t2 = __builtin_amdgcn_update_dpp(0, __builtin_bit_cast(int, x),
                                         0x4E /*quad_perm [2,3,0,1]*/,
                                         0xf, 0xf, false);
    return x + __builtin_bit_cast(float, t2);
}

// wave sum of QUAD-UNIFORM values -> total lands in lane 63 (4 DPP adds).
// shr4+shr8 leave row tails = sum of one representative per quad (x15 =
// x15+x11+x7+x3); bcast15/31 fold the 4 row tails into lane 63.
__device__ __forceinline__ float wave_sum_quaduniform_l63(float x) {
#define DPP_ADD(ctrl) do {                                                        \
        int t_ = __builtin_amdgcn_update_dpp(0, __builtin_bit_cast(int, x),       \
                                             (ctrl), 0xf, 0xf, false);            \
        x += __builtin_bit_cast(float, t_); } while (0)
    DPP_ADD(0x114);  // row_shr:4
    DPP_ADD(0x118);  // row_shr:8   -> row sums (one per quad) at row tails
    DPP_ADD(0x142);  // row_bcast:15
    DPP_ADD(0x143);  // row_bcast:31 -> lane 63 holds wave total
#undef DPP_ADD
    return x;
}

__device__ __forceinline__ float bcast_lane(float v, int l) {
    int r = __builtin_amdgcn_readlane(__builtin_bit_cast(int, v), l);
    return __builtin_bit_cast(float, r);
}

#define FORALL16(M) M(0) M(1) M(2) M(3) M(4) M(5) M(6) M(7) \
                    M(8) M(9) M(10) M(11) M(12) M(13) M(14) M(15)

// R18: cut LDS read traffic 2x via j-reuse. R17 post-mortem: per-CU DS pipe
// is the wall (~11.3 cyc marginal per ds_read_b128; 64 reads/CU/step = ~768
// of R16's 1176 cyc). Here each lane owns TWO units (j0,j1) over a 32-k
// chunk (kc=lane&3): reads 32 h1 (8 b128) for 64 MACs -- half the reads,
// same 64-VGPR W2 footprint (16 v2f per j). k-reduce = 2 quad_perm DPP
// butterflies (VALU pipe); wave reduce drops to 4 DPP (quad-uniform).
// Back to 1 batch element per block (128 blocks).
__global__ __launch_bounds__(NTHR, 2) void odenet_scan(
    const float* __restrict__ x,
    const float* __restrict__ W1, const float* __restrict__ b1,
    const float* __restrict__ W2, const float* __restrict__ b2,
    const float* __restrict__ W3, const float* __restrict__ b3,
    float* __restrict__ out) {

    const int b    = blockIdx.x;        // batch element
    const int tid  = threadIdx.x;
    const int w    = tid >> 6;          // wave 0..3
    const int lane = tid & 63;
    const int jg   = lane >> 2;         // j-pair group 0..15
    const int kc   = lane & 3;          // k-chunk [32*kc, 32*kc+32)
    const int j0   = (w << 5) | (jg << 1);     // owned output units j0, j0+1
    const int j1   = j0 + 1;
    const int kb   = kc << 5;

    // wave-private h1: 2 chunks x 68 floats (64 + 4 pad; chunk 1 at byte 272)
    __shared__ __align__(16) float h1buf[4][136];
    __shared__ __align__(16) float dyx[2][4];  // [parity][wave] dy partials

    // ---- W2 fragments: rows [kb, kb+32) of columns j0 and j1 (16 v2f each) --
    const float* c0p = W2 + j0;         // column j0, row stride HID
    const float* c1p = W2 + j1;
#define DECLW(i) v2f wp##i = {c0p[(kb + 2*(i) + 0) * HID],                        \
                              c0p[(kb + 2*(i) + 1) * HID]};                       \
                 v2f up##i = {c1p[(kb + 2*(i) + 0) * HID],                        \
                              c1p[(kb + 2*(i) + 1) * HID]};
    FORALL16(DECLW)
#undef DECLW
#define PINW(i) asm volatile("" : "+v"(wp##i), "+v"(up##i));
    FORALL16(PINW)
#undef PINW

    // layer-1 weights for the two h1 units this lane computes (k=lane, lane+64)
    float w1xa = W1[lane],      w1ya = W1[HID + lane],      b1a = b1[lane];
    float w1xb = W1[lane + 64], w1yb = W1[HID + lane + 64], b1b = b1[lane + 64];
    float b2j0 = b2[j0], b2j1 = b2[j1];
    float w3j0 = W3[j0], w3j1 = W3[j1], b3v = b3[0];
    asm volatile("" : "+v"(w1xa), "+v"(w1ya), "+v"(b1a),
                      "+v"(w1xb), "+v"(w1yb), "+v"(b1b),
                      "+v"(b2j0), "+v"(b2j1), "+v"(w3j0), "+v"(w3j1), "+v"(b3v));

    float y    = 0.0f;
    float ybuf = 0.0f;                  // all waves capture (symmetric arrival)
    if (w == 0 && lane == 0) out[b] = 0.0f;   // y_0 = 0

    // ---- x double-buffer: xbuf = current 64-step block, xnext = next ----
    float xbuf  = x[lane * BATCH + b];                 // block 0
    int   nb    = 64;                                  // next block base
    float xnext = x[min(nb + lane, T_STEPS - 1) * BATCH + b];
    float xv = bcast_lane(xbuf, 0);
    float ax = fmaf(xv, w1xa, b1a);     // x-side of layer 1 for t=0
    float bx = fmaf(xv, w1xb, b1b);

    // this lane's 32-k chunk: kc=0 -> byte 0, 1 -> 128, 2 -> 272, 3 -> 400
    const float4* h4 = (const float4*)((const char*)&h1buf[w][0] +
                                       ((kc >> 1) * 272 + (kc & 1) * 128));

    for (int t = 0; t < T_STEPS - 1; ++t) {
        const int tm = t & 63;

        // ---- layer 1 (critical path from y: fma+tanh+write only) ----
        float ha = fast_tanh(fmaf(y, w1ya, ax));
        float hb = fast_tanh(fmaf(y, w1yb, bx));
        h1buf[w][lane]      = ha;       // chunk 0 (k = lane)
        h1buf[w][68 + lane] = hb;       // chunk 1 (k = lane+64)

        // ---- layer 2: 8 b128 reads of own 32-k chunk, reused for j0 AND j1 --
        v2f a0 = {0.f, 0.f}, a1 = {0.f, 0.f};   // j0 accumulators
        v2f c0 = {0.f, 0.f}, c1 = {0.f, 0.f};   // j1 accumulators
        {
            float4 q;
#define FMAP(qi, WA, WB, UA, UB) q = h4[qi];                                      \
            { v2f lo = {q.x, q.y}, hi = {q.z, q.w};                               \
              a0 += WA * lo; a1 += WB * hi;                                       \
              c0 += UA * lo; c1 += UB * hi; }
            FMAP(0, wp0 , wp1 , up0 , up1 ) FMAP(1, wp2 , wp3 , up2 , up3 )
            FMAP(2, wp4 , wp5 , up4 , up5 ) FMAP(3, wp6 , wp7 , up6 , up7 )
            FMAP(4, wp8 , wp9 , up8 , up9 ) FMAP(5, wp10, wp11, up10, up11)
            FMAP(6, wp12, wp13, up12, up13) FMAP(7, wp14, wp15, up14, up15)
#undef FMAP
        }
        v2f as_ = a0 + a1;
        v2f cs_ = c0 + c1;

        // ---- k-reduce across the quad (2 DPP levels), tanh, layer 3 ----
        float z0 = quad_sum(as_.x + as_.y);          // full dot for unit j0
        float z1 = quad_sum(cs_.x + cs_.y);          // full dot for unit j1
        float h20 = fast_tanh(z0 + b2j0);
        float h21 = fast_tanh(z1 + b2j1);
        float dyv = fmaf(w3j0, h20, w3j1 * h21);     // quad-uniform
        float dyw = wave_sum_quaduniform_l63(dyv);
        if (lane == 63) dyx[t & 1][w] = dyw;         // direct from lane 63

        // ---- next step's x-side prep (y-independent; fills barrier wait) ----
        const int tmn = (t + 1) & 63;
        if (tmn == 0) {                              // rotate x blocks
            xbuf = xnext;
            nb += 64;
            xnext = x[min(nb + lane, T_STEPS - 1) * BATCH + b];
        }
        float xvn = bcast_lane(xbuf, tmn);
        float axn = fmaf(xvn, w1xa, b1a);
        float bxn = fmaf(xvn, w1xb, b1b);

        // ---- lgkm-only barrier (4 waves): stores/x-loads stay in flight ----
        asm volatile("s_waitcnt lgkmcnt(0)\n\ts_barrier" ::: "memory");

        float4 d = *(const float4*)&dyx[t & 1][0];   // one broadcast b128
        y += ((d.x + d.y) + (d.z + d.w)) + b3v;      // DT = 1.0

        ybuf = (lane == tm) ? y : ybuf;              // all waves (symmetric)
        if (w == 0 && tm == 63)
            out[(t - 62 + lane) * BATCH + b] = ybuf;

        ax = axn; bx = bxn;
    }
    // tail: t=8128..8190 captured y_8129..y_8191 in lanes 0..62
    if (w == 0 && lane < 63)
        out[(T_STEPS - 63 + lane) * BATCH + b] = ybuf;
}

extern "C" void kernel_launch(void* const* d_in, const int* in_sizes, int n_in,
                              void* d_out, int out_size, void* d_ws, size_t ws_size,
                              hipStream_t stream) {
    const float* x  = (const float*)d_in[0];
    const float* W1 = (const float*)d_in[1];
    const float* b1 = (const float*)d_in[2];
    const float* W2 = (const float*)d_in[3];
    const float* b2 = (const float*)d_in[4];
    const float* W3 = (const float*)d_in[5];
    const float* b3 = (const float*)d_in[6];

    odenet_scan<<<dim3(BATCH), dim3(NTHR), 0, stream>>>(
        x, W1, b1, W2, b2, W3, b3, (float*)d_out);
}